// Round 15
// baseline (139.447 us; speedup 1.0000x reference)
//
#include <hip/hip_runtime.h>

#define B_   8
#define C_   64
#define W_   128
#define H_   128
#define K_   9
#define OUT_ 64
#define NPIX (B_*W_*H_)      // 131072
#define EPS_ 1e-5f

typedef __attribute__((ext_vector_type(8))) short bf16x8;
typedef __attribute__((ext_vector_type(4))) float f32x4;

// ---------------- workspace layout (float offsets) ----------------
#define FEATBF_OFF  0                      // B*W*H*C bf16 (4194304 f)
#define XPRE_OFF    4194304                // B*64*W*H bf16 (4194304 f)
#define OFFPRE_OFF  8388608                // B*9*W*H = 1179648
#define OFFH_OFF    9568256                // 4*B*9*W*H = 4718592 (c-split partials)
#define WT_OFF      14286848               // 9*64*64 bf16 (18432 f)
#define WP_OFF      14305280               // 64*81 = 5184
#define BNSTATS_OFF 14310464               // 18
#define BNAB_OFF    14310482               // 18
#define GSTATS_OFF  14310500               // 256
#define GNFIN_OFF   14310756               // 256
#define STATS_BYTES ((18+18+256+256)*sizeof(float))

__device__ __forceinline__ unsigned pack2bf(float a, float b) {
    union { float f; unsigned u; } ua, ub;
    ua.f = a; ub.f = b;
    unsigned x = ua.u, y = ub.u;
    x += 0x7fffu + ((x >> 16) & 1u);       // RNE to bf16
    y += 0x7fffu + ((y >> 16) & 1u);
    return (x >> 16) | (y & 0xffff0000u);
}
__device__ __forceinline__ float bflo(unsigned u) {
    union { unsigned u; float f; } v; v.u = u << 16; return v.f;
}
__device__ __forceinline__ float bfhi(unsigned u) {
    union { unsigned u; float f; } v; v.u = u & 0xffff0000u; return v.f;
}

// ---------------- NCHW -> NHWC bf16 transpose of f (sampling path only) ----------------
__global__ __launch_bounds__(256) void k_nhwc(const float* __restrict__ f,
                                              unsigned short* __restrict__ featbf) {
    __shared__ float tile[64][65];
    int bid = blockIdx.x;
    int ht = bid & 1;            // 64-high h tile
    int w  = (bid >> 1) & 127;
    int b  = bid >> 8;
    int t  = threadIdx.x;
    int lh = t & 63;
    int c0 = (t >> 6) * 16;
    const float* fp = f + (((b*64)*128 + w)*128) + ht*64 + lh;
#pragma unroll
    for (int i = 0; i < 16; i++) {
        int c = c0 + i;
        tile[c][lh] = fp[c*16384];
    }
    __syncthreads();
    int lc = t & 63;
    int h0 = (t >> 6) * 16;
    unsigned short* obf = featbf + ((size_t)((b*128 + w)*128) + ht*64)*64 + lc;
#pragma unroll
    for (int i = 0; i < 16; i++) {
        int hr = h0 + i;
        union { float f; unsigned u; } v; v.f = tile[lc][hr];
        unsigned x = v.u + 0x7fffu + ((v.u >> 16) & 1u);
        obf[(size_t)hr*64] = (unsigned short)(x >> 16);
    }
}

// ---------------- w_dsc (O,C,K) -> wTbf[k][o][c] bf16 ----------------
__global__ void k_wt(const float* __restrict__ w_dsc, unsigned short* __restrict__ wTbf) {
    int i = blockIdx.x*256 + threadIdx.x;       // < 36864
    if (i >= 9*64*64) return;
    int c = i & 63;
    int o = (i >> 6) & 63;
    int k = i >> 12;
    union { float f; unsigned u; } v;
    v.f = w_dsc[(o*64 + c)*9 + k];
    unsigned x = v.u + 0x7fffu + ((v.u >> 16) & 1u);
    wTbf[i] = (unsigned short)(x >> 16);
}

// ---------------- w_off (18,64,3,3) -> wP[c][dw][ck][dh] ----------------
__global__ void k_wp(const float* __restrict__ w_off, float* __restrict__ wP) {
    int i = blockIdx.x*256 + threadIdx.x;       // < 5184
    if (i >= 64*81) return;
    int c    = i / 81;
    int rem  = i % 81;
    int dw   = rem / 27;
    int rem2 = rem % 27;
    int ck   = rem2 / 3;
    int dh   = rem2 % 3;
    wP[i] = w_off[ck*576 + c*9 + dw*3 + dh];
}

// ---------------- 3x3 conv, c-split x4, shuffle taps, LDS weights ----------------
// fp32 path REQUIRED (offset feeds a discontinuous sampler; see R7 failure).
// b_off dropped: per-channel constant cancels exactly through BN.
// R12-R14 evidence: conv time invariant to occupancy/load-count/FMA-amortization
// -> per-CU SCALAR pipe is the bottleneck (every wave streams 81 uniform
// weights/c via s_load, one scalar unit per CU, 112-SGPR budget forces
// re-loads). Fix: weights staged in LDS once, read via DS pipe into VGPRs
// (uniform-addr ds_read broadcasts conflict-free; no scalar serialization).
__global__ __launch_bounds__(128) void k_conv_off(const float* __restrict__ f,
                                                  const float* __restrict__ wP,
                                                  float* __restrict__ off_half) {
    __shared__ float wsh[16*84];    // 84-stride keeps each c-slice 16B-aligned
    int t   = threadIdx.x;          // 0..127 = h
    int bid = blockIdx.x;
    int b   = bid & 7;              // XCD swizzle: each XCD owns one batch
    int w   = (bid >> 3) & 127;     // wave-uniform
    int cq  = bid >> 10;            // c-quarter 0..3 (wave-uniform)
    int h   = t;

    {
        const float* src = wP + cq*16*81;
        for (int i = t; i < 1296; i += 128) {
            int c = i / 81, j = i - c*81;
            wsh[c*84 + j] = src[i];
        }
    }
    __syncthreads();

    float em = (h == 0)   ? 0.f : 1.f;
    float ep = (h == 127) ? 0.f : 1.f;

    const float* fb = f + (size_t)b*1048576 + (size_t)(cq*16)*16384 + (size_t)w*128;

    float acc[9];
#pragma unroll
    for (int ck = 0; ck < 9; ck++) acc[ck] = 0.f;

#pragma unroll 4
    for (int c = 0; c < 16; c++) {
        const float* p  = fb + c*16384;
        const float* wc = wsh + c*84;
#pragma unroll
        for (int dw = -1; dw <= 1; dw++) {
            int wy = w + dw;
            if ((unsigned)wy < 128u) {           // uniform branch
                const float* q = p + dw*128;
                float v1 = q[h];
                float v0 = __shfl_up(v1, 1);
                float v2 = __shfl_down(v1, 1);
                if (t == 64) v0 = q[63];         // cross-wave seam
                if (t == 63) v2 = q[64];
                v0 *= em; v2 *= ep;
                const float* ww = wc + (dw+1)*27;
#pragma unroll
                for (int ck = 0; ck < 9; ck++)
                    acc[ck] += v0*ww[ck*3] + v1*ww[ck*3+1] + v2*ww[ck*3+2];
            }
        }
    }

    float* dst = off_half + (size_t)cq*1179648;
    int pixoff = (w << 7) + h;
#pragma unroll
    for (int ck = 0; ck < 9; ck++)
        dst[((b*9 + ck) << 14) + pixoff] = acc[ck];
}

// ---------------- sum quarters -> off_pre, BN stats ----------------
__global__ __launch_bounds__(256) void k_bn_stats(const float* __restrict__ off_half,
                                                  float* __restrict__ off_pre,
                                                  float* __restrict__ bnstats) {
    __shared__ float wred[4][2];
    int bid = blockIdx.x;           // 288 = b*36 + ck*4 + wq
    int b  = bid / 36;
    int rem = bid % 36;
    int ck = rem / 4;
    int wq = rem % 4;
    int t  = threadIdx.x;
    int base4 = (((b*9+ck) << 14) + wq*4096) >> 2;

    const float4* h0 = (const float4*)off_half;
    const float4* h1 = (const float4*)(off_half + 1179648);
    const float4* h2 = (const float4*)(off_half + 2359296);
    const float4* h3 = (const float4*)(off_half + 3538944);
    float4* op = (float4*)off_pre;

    float s = 0.f, q = 0.f;
#pragma unroll
    for (int i = 0; i < 4; i++) {
        int idx = base4 + t + i*256;
        float4 a = h0[idx], bb = h1[idx], cc = h2[idx], dd = h3[idx];
        float4 v;
        v.x = (a.x + bb.x) + (cc.x + dd.x);
        v.y = (a.y + bb.y) + (cc.y + dd.y);
        v.z = (a.z + bb.z) + (cc.z + dd.z);
        v.w = (a.w + bb.w) + (cc.w + dd.w);
        op[idx] = v;
        s += v.x + v.y + v.z + v.w;
        q += v.x*v.x + v.y*v.y + v.z*v.z + v.w*v.w;
    }
    for (int off = 32; off; off >>= 1) {
        s += __shfl_down(s, off);
        q += __shfl_down(q, off);
    }
    if ((t & 63) == 0) { wred[t >> 6][0] = s; wred[t >> 6][1] = q; }
    __syncthreads();
    if (t == 0) atomicAdd(&bnstats[ck*2],   wred[0][0]+wred[1][0]+wred[2][0]+wred[3][0]);
    if (t == 1) atomicAdd(&bnstats[ck*2+1], wred[0][1]+wred[1][1]+wred[2][1]+wred[3][1]);
}

// ---------------- BN finalize ----------------
__global__ void k_bn_fin(const float* __restrict__ bnstats,
                         const float* __restrict__ bn_gamma,
                         const float* __restrict__ bn_beta,
                         float* __restrict__ bnAB) {
    int t = threadIdx.x;
    if (t < 9) {
        float n    = (float)NPIX;
        float mean = bnstats[t*2] / n;
        float var  = bnstats[t*2+1] / n - mean*mean;
        float A    = bn_gamma[t] / sqrtf(var + EPS_);
        bnAB[t*2]   = A;
        bnAB[t*2+1] = bn_beta[t] - mean * A;
    }
}

// ---------------- fused: offsets, 2-tap y-lerp sample (bf16), MFMA strip conv, GN stats ----------------
__global__ __launch_bounds__(256) void k_sample_dsc(const unsigned short* __restrict__ featbf,
                                                    const float* __restrict__ off_pre,
                                                    const float* __restrict__ bnAB,
                                                    const unsigned short* __restrict__ wTbf,
                                                    const float* __restrict__ b_dsc,
                                                    unsigned short* __restrict__ xprebf,
                                                    float* __restrict__ gstats) {
    __shared__ __align__(16) unsigned char lds_samp[128*128]; // [h][c] bf16, XOR-swizzled rows
    __shared__ __align__(16) unsigned char lds_wk[64*128];    // [o][c] bf16, XOR-swizzled rows
    __shared__ float ynew[9][128];
    __shared__ float red[16][2];

    int t = threadIdx.x;
    // XCD swizzle: 1024 blocks = 8 XCD x 128; each XCD owns one b
    int b = blockIdx.x & 7, w = blockIdx.x >> 3;

    if (t < 128) {
        int h = t;
        float y[9];
#pragma unroll
        for (int ck = 0; ck < 9; ck++) {
            float v = off_pre[((b*9+ck) << 14) + (w << 7) + h];
            y[ck] = tanhf(bnAB[ck*2]*v + bnAB[ck*2+1]);
        }
        float ofn[9];
        ofn[4] = 0.f;
        ofn[5] = y[5]; ofn[6] = y[5]+y[6]; ofn[7] = y[5]+y[6]+y[7];
        ofn[3] = y[3]; ofn[2] = y[3]+y[2]; ofn[1] = y[3]+y[2]+y[1];
        ofn[0] = y[0]; ofn[8] = y[8];
#pragma unroll
        for (int k = 0; k < 9; k++) ynew[k][h] = (float)w + ofn[k];
    }
    if (t < 16) { red[t][0] = 0.f; red[t][1] = 0.f; }

    f32x4 acc[2][4];
#pragma unroll
    for (int mi = 0; mi < 2; mi++)
#pragma unroll
        for (int ni = 0; ni < 4; ni++) {
            acc[mi][ni][0] = 0.f; acc[mi][ni][1] = 0.f;
            acc[mi][ni][2] = 0.f; acc[mi][ni][3] = 0.f;
        }

    int lane = t & 63, wv = t >> 6;
    int m0 = wv * 32;                 // wave's 32-row M tile
    int lm = lane & 15, lk = lane >> 4;
    int hs = t >> 1;                  // sampling row
    int cq = (t & 1) * 4;             // uint4 offset (32 ch half)

    __syncthreads();

    for (int k = 0; k < 9; k++) {
        if (k) __syncthreads();       // previous iter's MFMA reads done

        // ---- stage weight k-slice [64 o][64 c] bf16 into swizzled LDS ----
        {
            const uint4* src = (const uint4*)(wTbf + (k << 12));
#pragma unroll
            for (int i = 0; i < 2; i++) {
                int ci = t + i*256;                 // 0..511 16B chunks
                uint4 v = src[ci];
                int o  = ci >> 3;
                int cb = (ci & 7) << 4;
                *(uint4*)(lds_wk + o*128 + (cb ^ ((o & 7) << 4))) = v;
            }
        }

        // ---- 2-tap y-lerp sample, row hs, 32 ch -> bf16 LDS ----
        // x_s is integer -> x-weights are {1,0} in-bounds, exact 0 outside
        {
            int x0 = k - 4 + hs;
            unsigned char* dst = lds_samp + hs*128;
            int bcol0 = (t & 1) * 64;
            if ((unsigned)x0 < 127u) {
                float ys = ynew[k][hs];
                int y0  = (int)floorf(ys);
                int y0c = min(max(y0, 0), 127), y1c = min(max(y0+1, 0), 127);
                float wa = (float)y1c - ys;     // top tap weight
                float wc = ys - (float)y0c;     // bottom tap weight
                const unsigned short* pb = featbf + ((size_t)b << 20);
                const uint4* p0 = (const uint4*)(pb + (y0c*128 + x0)*64) + cq;
                const uint4* p1 = (const uint4*)(pb + (y1c*128 + x0)*64) + cq;
#pragma unroll
                for (int ci = 0; ci < 4; ci++) {
                    uint4 a = p0[ci], c = p1[ci];
                    uint4 u;
                    u.x = pack2bf(bflo(a.x)*wa + bflo(c.x)*wc, bfhi(a.x)*wa + bfhi(c.x)*wc);
                    u.y = pack2bf(bflo(a.y)*wa + bflo(c.y)*wc, bfhi(a.y)*wa + bfhi(c.y)*wc);
                    u.z = pack2bf(bflo(a.z)*wa + bflo(c.z)*wc, bfhi(a.z)*wa + bfhi(c.z)*wc);
                    u.w = pack2bf(bflo(a.w)*wa + bflo(c.w)*wc, bfhi(a.w)*wa + bfhi(c.w)*wc);
                    *(uint4*)(dst + ((bcol0 + ci*16) ^ ((hs & 7) << 4))) = u;
                }
            } else {
                uint4 z = make_uint4(0,0,0,0);
#pragma unroll
                for (int ci = 0; ci < 4; ci++)
                    *(uint4*)(dst + ((bcol0 + ci*16) ^ ((hs & 7) << 4))) = z;
            }
        }
        __syncthreads();

        // ---- MFMA: acc[mi][ni] += A[32k-slice] * B ----
#pragma unroll
        for (int ks = 0; ks < 2; ks++) {
            bf16x8 af[2], bfr[4];
#pragma unroll
            for (int mi = 0; mi < 2; mi++) {
                int h = m0 + mi*16 + lm;
                af[mi] = *(const bf16x8*)(lds_samp + h*128 + ((ks*64 + lk*16) ^ ((h & 7) << 4)));
            }
#pragma unroll
            for (int ni = 0; ni < 4; ni++) {
                int o = ni*16 + lm;
                bfr[ni] = *(const bf16x8*)(lds_wk + o*128 + ((ks*64 + lk*16) ^ ((o & 7) << 4)));
            }
#pragma unroll
            for (int mi = 0; mi < 2; mi++)
#pragma unroll
                for (int ni = 0; ni < 4; ni++)
                    acc[mi][ni] = __builtin_amdgcn_mfma_f32_16x16x32_bf16(af[mi], bfr[ni], acc[mi][ni], 0, 0, 0);
        }
    }

    // ---- epilogue: bias, bf16 xpre write (C/D: row=lk*4+reg, col=lm), GN stats ----
#pragma unroll
    for (int ni = 0; ni < 4; ni++) {
        int o = ni*16 + lm;
        float bias = b_dsc[o];
        float s1 = 0.f, s2 = 0.f;
#pragma unroll
        for (int mi = 0; mi < 2; mi++) {
            float4 r;
            r.x = acc[mi][ni][0] + bias;
            r.y = acc[mi][ni][1] + bias;
            r.z = acc[mi][ni][2] + bias;
            r.w = acc[mi][ni][3] + bias;
            s1 += r.x + r.y + r.z + r.w;
            s2 += r.x*r.x + r.y*r.y + r.z*r.z + r.w*r.w;
            int h = m0 + mi*16 + lk*4;
            uint2 u2;
            u2.x = pack2bf(r.x, r.y);
            u2.y = pack2bf(r.z, r.w);
            *(uint2*)(xprebf + (((b*64 + o) << 14) + (w << 7) + h)) = u2;
        }
        s1 += __shfl_xor(s1, 1);  s1 += __shfl_xor(s1, 2);
        s1 += __shfl_xor(s1, 16); s1 += __shfl_xor(s1, 32);
        s2 += __shfl_xor(s2, 1);  s2 += __shfl_xor(s2, 2);
        s2 += __shfl_xor(s2, 16); s2 += __shfl_xor(s2, 32);
        if (lk == 0 && (lm & 3) == 0) {
            atomicAdd(&red[ni*4 + (lm >> 2)][0], s1);
            atomicAdd(&red[ni*4 + (lm >> 2)][1], s2);
        }
    }
    __syncthreads();
    if (t < 16) {
        atomicAdd(&gstats[(b*16 + t)*2],   red[t][0]);
        atomicAdd(&gstats[(b*16 + t)*2+1], red[t][1]);
    }
}

// ---------------- GN finalize ----------------
__global__ void k_gn_fin(const float* __restrict__ gstats, float* __restrict__ gnfin) {
    int t = threadIdx.x;
    if (t < 128) {
        float n    = 65536.f;           // 4 ch * 128 * 128
        float mean = gstats[t*2] / n;
        float var  = gstats[t*2+1] / n - mean*mean;
        gnfin[t*2]   = mean;
        gnfin[t*2+1] = 1.0f / sqrtf(var + EPS_);
    }
}

// ---------------- GN apply + ReLU (bf16 in, fp32 out) ----------------
__global__ __launch_bounds__(256) void k_gn_apply(const unsigned short* __restrict__ xprebf,
                                                  const float* __restrict__ gnfin,
                                                  const float* __restrict__ gn_gamma,
                                                  const float* __restrict__ gn_beta,
                                                  float* __restrict__ out) {
    int i8  = blockIdx.x*256 + threadIdx.x;
    int idx = i8 * 8;
    int o = (idx >> 14) & 63;
    int b = idx >> 20;
    int g = o >> 2;
    float mean = gnfin[(b*16+g)*2];
    float istd = gnfin[(b*16+g)*2+1];
    float ga = gn_gamma[o] * istd;
    float be = gn_beta[o] - mean * ga;
    uint4 v = *(const uint4*)(xprebf + idx);
    float4 r0, r1;
    r0.x = fmaxf(bflo(v.x)*ga + be, 0.f);
    r0.y = fmaxf(bfhi(v.x)*ga + be, 0.f);
    r0.z = fmaxf(bflo(v.y)*ga + be, 0.f);
    r0.w = fmaxf(bfhi(v.y)*ga + be, 0.f);
    r1.x = fmaxf(bflo(v.z)*ga + be, 0.f);
    r1.y = fmaxf(bfhi(v.z)*ga + be, 0.f);
    r1.z = fmaxf(bflo(v.w)*ga + be, 0.f);
    r1.w = fmaxf(bfhi(v.w)*ga + be, 0.f);
    *(float4*)(out + idx)     = r0;
    *(float4*)(out + idx + 4) = r1;
}

extern "C" void kernel_launch(void* const* d_in, const int* in_sizes, int n_in,
                              void* d_out, int out_size, void* d_ws, size_t ws_size,
                              hipStream_t stream) {
    const float* f        = (const float*)d_in[0];
    const float* w_off    = (const float*)d_in[1];
    const float* bn_gamma = (const float*)d_in[3];
    const float* bn_beta  = (const float*)d_in[4];
    const float* w_dsc    = (const float*)d_in[5];
    const float* b_dsc    = (const float*)d_in[6];
    const float* gn_gamma = (const float*)d_in[7];
    const float* gn_beta  = (const float*)d_in[8];

    float* ws      = (float*)d_ws;
    unsigned short* featbf = (unsigned short*)(ws + FEATBF_OFF);
    unsigned short* xprebf = (unsigned short*)(ws + XPRE_OFF);
    float* off_pre = ws + OFFPRE_OFF;
    float* off_half= ws + OFFH_OFF;
    unsigned short* wTbf = (unsigned short*)(ws + WT_OFF);
    float* wP      = ws + WP_OFF;
    float* bnstats = ws + BNSTATS_OFF;
    float* bnAB    = ws + BNAB_OFF;
    float* gstats  = ws + GSTATS_OFF;
    float* gnfin   = ws + GNFIN_OFF;

    hipMemsetAsync(bnstats, 0, STATS_BYTES, stream);

    k_nhwc<<<2048, 256, 0, stream>>>(f, featbf);
    k_wt<<<144, 256, 0, stream>>>(w_dsc, wTbf);
    k_wp<<<21, 256, 0, stream>>>(w_off, wP);
    k_conv_off<<<4096, 128, 0, stream>>>(f, wP, off_half);
    k_bn_stats<<<288, 256, 0, stream>>>(off_half, off_pre, bnstats);
    k_bn_fin<<<1, 32, 0, stream>>>(bnstats, bn_gamma, bn_beta, bnAB);
    k_sample_dsc<<<1024, 256, 0, stream>>>(featbf, off_pre, bnAB, wTbf, b_dsc, xprebf, gstats);
    k_gn_fin<<<1, 128, 0, stream>>>(gstats, gnfin);
    k_gn_apply<<<4096, 256, 0, stream>>>(xprebf, gnfin, gn_gamma, gn_beta, (float*)d_out);
}

// Round 16
// 126.338 us; speedup vs baseline: 1.1038x; 1.1038x over previous
//
#include <hip/hip_runtime.h>

#define B_   8
#define C_   64
#define W_   128
#define H_   128
#define K_   9
#define OUT_ 64
#define NPIX (B_*W_*H_)      // 131072
#define EPS_ 1e-5f

typedef __attribute__((ext_vector_type(8))) short bf16x8;
typedef __attribute__((ext_vector_type(4))) float f32x4;

// ---------------- workspace layout (float offsets) ----------------
#define FEATBF_OFF  0                      // B*W*H*C bf16 (4194304 f)
#define XPRE_OFF    4194304                // B*64*W*H bf16 (4194304 f)
#define OFFPRE_OFF  8388608                // B*9*W*H = 1179648
#define OFFH_OFF    9568256                // 4*B*9*W*H = 4718592 (c-split partials)
#define WT_OFF      14286848               // 9*64*64 bf16 (18432 f)
#define WP_OFF      14305280               // 64*81 = 5184
#define BNSTATS_OFF 14310464               // 18
#define GSTATS_OFF  14310500               // 256
#define STATS_BYTES ((18+18+256+256)*sizeof(float))

__device__ __forceinline__ unsigned pack2bf(float a, float b) {
    union { float f; unsigned u; } ua, ub;
    ua.f = a; ub.f = b;
    unsigned x = ua.u, y = ub.u;
    x += 0x7fffu + ((x >> 16) & 1u);       // RNE to bf16
    y += 0x7fffu + ((y >> 16) & 1u);
    return (x >> 16) | (y & 0xffff0000u);
}
__device__ __forceinline__ float bflo(unsigned u) {
    union { unsigned u; float f; } v; v.u = u << 16; return v.f;
}
__device__ __forceinline__ float bfhi(unsigned u) {
    union { unsigned u; float f; } v; v.u = u & 0xffff0000u; return v.f;
}

// ---------------- NCHW -> NHWC bf16 transpose of f (sampling path only) ----------------
__global__ __launch_bounds__(256) void k_nhwc(const float* __restrict__ f,
                                              unsigned short* __restrict__ featbf) {
    __shared__ float tile[64][65];
    int bid = blockIdx.x;
    int ht = bid & 1;            // 64-high h tile
    int w  = (bid >> 1) & 127;
    int b  = bid >> 8;
    int t  = threadIdx.x;
    int lh = t & 63;
    int c0 = (t >> 6) * 16;
    const float* fp = f + (((b*64)*128 + w)*128) + ht*64 + lh;
#pragma unroll
    for (int i = 0; i < 16; i++) {
        int c = c0 + i;
        tile[c][lh] = fp[c*16384];
    }
    __syncthreads();
    int lc = t & 63;
    int h0 = (t >> 6) * 16;
    unsigned short* obf = featbf + ((size_t)((b*128 + w)*128) + ht*64)*64 + lc;
#pragma unroll
    for (int i = 0; i < 16; i++) {
        int hr = h0 + i;
        union { float f; unsigned u; } v; v.f = tile[lc][hr];
        unsigned x = v.u + 0x7fffu + ((v.u >> 16) & 1u);
        obf[(size_t)hr*64] = (unsigned short)(x >> 16);
    }
}

// ---------------- weight prep: w_dsc -> wTbf[k][o][c] bf16 ; w_off -> wP[c][dw][ck][dh] ----------------
__global__ void k_wprep(const float* __restrict__ w_dsc, unsigned short* __restrict__ wTbf,
                        const float* __restrict__ w_off, float* __restrict__ wP) {
    int bid = blockIdx.x;
    if (bid < 144) {
        int i = bid*256 + threadIdx.x;       // < 36864
        if (i >= 9*64*64) return;
        int c = i & 63;
        int o = (i >> 6) & 63;
        int k = i >> 12;
        union { float f; unsigned u; } v;
        v.f = w_dsc[(o*64 + c)*9 + k];
        unsigned x = v.u + 0x7fffu + ((v.u >> 16) & 1u);
        wTbf[i] = (unsigned short)(x >> 16);
    } else {
        int i = (bid-144)*256 + threadIdx.x; // < 5184
        if (i >= 64*81) return;
        int c    = i / 81;
        int rem  = i % 81;
        int dw   = rem / 27;
        int rem2 = rem % 27;
        int ck   = rem2 / 3;
        int dh   = rem2 % 3;
        wP[i] = w_off[ck*576 + c*9 + dw*3 + dh];
    }
}

// ---------------- 3x3 conv, c-split x4, shuffle taps (NCHW f, lane = h) ----------------
// fp32 path REQUIRED (offset feeds a discontinuous sampler; see R7 failure).
// b_off dropped: per-channel constant cancels exactly through BN.
// R13 form — best measured (45us). R14 w-strip (52) and R15 LDS-weights (65)
// both regressed: per-CU shared pipes (scalar / DS / TA) all cost ~the same
// for the 81-weights-per-c stream; this variant balances them best.
__global__ __launch_bounds__(128) void k_conv_off(const float* __restrict__ f,
                                                  const float* __restrict__ wP,
                                                  float* __restrict__ off_half) {
    int t   = threadIdx.x;          // 0..127 = h
    int bid = blockIdx.x;
    int b   = bid & 7;              // XCD swizzle: each XCD owns one batch
    int w   = (bid >> 3) & 127;     // wave-uniform
    int cq  = bid >> 10;            // c-quarter 0..3 (wave-uniform)
    int h   = t;

    float em = (h == 0)   ? 0.f : 1.f;
    float ep = (h == 127) ? 0.f : 1.f;

    const float* fb = f + (size_t)b*1048576 + (size_t)(cq*16)*16384 + (size_t)w*128;
    const float* wb = wP + cq*16*81;

    float acc[9];
#pragma unroll
    for (int ck = 0; ck < 9; ck++) acc[ck] = 0.f;

#pragma unroll 4
    for (int c = 0; c < 16; c++) {
        const float* p  = fb + c*16384;
        const float* wc = wb + c*81;
#pragma unroll
        for (int dw = -1; dw <= 1; dw++) {
            int wy = w + dw;
            if ((unsigned)wy < 128u) {           // uniform branch
                const float* q = p + dw*128;
                float v1 = q[h];
                float v0 = __shfl_up(v1, 1);
                float v2 = __shfl_down(v1, 1);
                if (t == 64) v0 = q[63];         // cross-wave seam
                if (t == 63) v2 = q[64];
                v0 *= em; v2 *= ep;
                const float* ww = wc + (dw+1)*27;
#pragma unroll
                for (int ck = 0; ck < 9; ck++)
                    acc[ck] += v0*ww[ck*3] + v1*ww[ck*3+1] + v2*ww[ck*3+2];
            }
        }
    }

    float* dst = off_half + (size_t)cq*1179648;
    int pixoff = (w << 7) + h;
#pragma unroll
    for (int ck = 0; ck < 9; ck++)
        dst[((b*9 + ck) << 14) + pixoff] = acc[ck];
}

// ---------------- sum quarters -> off_pre, BN stats ----------------
__global__ __launch_bounds__(256) void k_bn_stats(const float* __restrict__ off_half,
                                                  float* __restrict__ off_pre,
                                                  float* __restrict__ bnstats) {
    __shared__ float wred[4][2];
    int bid = blockIdx.x;           // 288 = b*36 + ck*4 + wq
    int b  = bid / 36;
    int rem = bid % 36;
    int ck = rem / 4;
    int wq = rem % 4;
    int t  = threadIdx.x;
    int base4 = (((b*9+ck) << 14) + wq*4096) >> 2;

    const float4* h0 = (const float4*)off_half;
    const float4* h1 = (const float4*)(off_half + 1179648);
    const float4* h2 = (const float4*)(off_half + 2359296);
    const float4* h3 = (const float4*)(off_half + 3538944);
    float4* op = (float4*)off_pre;

    float s = 0.f, q = 0.f;
#pragma unroll
    for (int i = 0; i < 4; i++) {
        int idx = base4 + t + i*256;
        float4 a = h0[idx], bb = h1[idx], cc = h2[idx], dd = h3[idx];
        float4 v;
        v.x = (a.x + bb.x) + (cc.x + dd.x);
        v.y = (a.y + bb.y) + (cc.y + dd.y);
        v.z = (a.z + bb.z) + (cc.z + dd.z);
        v.w = (a.w + bb.w) + (cc.w + dd.w);
        op[idx] = v;
        s += v.x + v.y + v.z + v.w;
        q += v.x*v.x + v.y*v.y + v.z*v.z + v.w*v.w;
    }
    for (int off = 32; off; off >>= 1) {
        s += __shfl_down(s, off);
        q += __shfl_down(q, off);
    }
    if ((t & 63) == 0) { wred[t >> 6][0] = s; wred[t >> 6][1] = q; }
    __syncthreads();
    if (t == 0) atomicAdd(&bnstats[ck*2],   wred[0][0]+wred[1][0]+wred[2][0]+wred[3][0]);
    if (t == 1) atomicAdd(&bnstats[ck*2+1], wred[0][1]+wred[1][1]+wred[2][1]+wred[3][1]);
}

// ---------------- fused: BN-finalize, offsets, 2-tap sample (bf16), MFMA, GN stats ----------------
__global__ __launch_bounds__(256) void k_sample_dsc(const unsigned short* __restrict__ featbf,
                                                    const float* __restrict__ off_pre,
                                                    const float* __restrict__ bnstats,
                                                    const float* __restrict__ bn_gamma,
                                                    const float* __restrict__ bn_beta,
                                                    const unsigned short* __restrict__ wTbf,
                                                    const float* __restrict__ b_dsc,
                                                    unsigned short* __restrict__ xprebf,
                                                    float* __restrict__ gstats) {
    __shared__ __align__(16) unsigned char lds_samp[128*128]; // [h][c] bf16, XOR-swizzled rows
    __shared__ __align__(16) unsigned char lds_wk[64*128];    // [o][c] bf16, XOR-swizzled rows
    __shared__ float ynew[9][128];
    __shared__ float red[16][2];
    __shared__ float bnab[18];

    int t = threadIdx.x;
    // XCD swizzle: 1024 blocks = 8 XCD x 128; each XCD owns one b
    int b = blockIdx.x & 7, w = blockIdx.x >> 3;

    // BN finalize (folded k_bn_fin): per-block recompute, trivial
    if (t < 9) {
        float n    = (float)NPIX;
        float mean = bnstats[t*2] / n;
        float var  = bnstats[t*2+1] / n - mean*mean;
        float A    = bn_gamma[t] / sqrtf(var + EPS_);
        bnab[t*2]   = A;
        bnab[t*2+1] = bn_beta[t] - mean * A;
    }
    if (t < 16) { red[t][0] = 0.f; red[t][1] = 0.f; }
    __syncthreads();

    if (t < 128) {
        int h = t;
        float y[9];
#pragma unroll
        for (int ck = 0; ck < 9; ck++) {
            float v = off_pre[((b*9+ck) << 14) + (w << 7) + h];
            y[ck] = tanhf(bnab[ck*2]*v + bnab[ck*2+1]);
        }
        float ofn[9];
        ofn[4] = 0.f;
        ofn[5] = y[5]; ofn[6] = y[5]+y[6]; ofn[7] = y[5]+y[6]+y[7];
        ofn[3] = y[3]; ofn[2] = y[3]+y[2]; ofn[1] = y[3]+y[2]+y[1];
        ofn[0] = y[0]; ofn[8] = y[8];
#pragma unroll
        for (int k = 0; k < 9; k++) ynew[k][h] = (float)w + ofn[k];
    }

    f32x4 acc[2][4];
#pragma unroll
    for (int mi = 0; mi < 2; mi++)
#pragma unroll
        for (int ni = 0; ni < 4; ni++) {
            acc[mi][ni][0] = 0.f; acc[mi][ni][1] = 0.f;
            acc[mi][ni][2] = 0.f; acc[mi][ni][3] = 0.f;
        }

    int lane = t & 63, wv = t >> 6;
    int m0 = wv * 32;                 // wave's 32-row M tile
    int lm = lane & 15, lk = lane >> 4;
    int hs = t >> 1;                  // sampling row
    int cq = (t & 1) * 4;             // uint4 offset (32 ch half)

    // prefetch k=0 weights into regs
    uint4 wv0, wv1;
    {
        const uint4* src = (const uint4*)wTbf;
        wv0 = src[t];
        wv1 = src[t + 256];
    }

    __syncthreads();

    for (int k = 0; k < 9; k++) {
        if (k) __syncthreads();       // previous iter's MFMA reads done

        // ---- write prefetched weight k-slice [64 o][64 c] bf16 into swizzled LDS ----
        {
#pragma unroll
            for (int i = 0; i < 2; i++) {
                int ci = t + i*256;                 // 0..511 16B chunks
                uint4 v = (i == 0) ? wv0 : wv1;
                int o  = ci >> 3;
                int cb = (ci & 7) << 4;
                *(uint4*)(lds_wk + o*128 + (cb ^ ((o & 7) << 4))) = v;
            }
        }

        // ---- 2-tap y-lerp sample, row hs, 32 ch -> bf16 LDS ----
        // x_s is integer -> x-weights are {1,0} in-bounds, exact 0 outside
        {
            int x0 = k - 4 + hs;
            unsigned char* dst = lds_samp + hs*128;
            int bcol0 = (t & 1) * 64;
            if ((unsigned)x0 < 127u) {
                float ys = ynew[k][hs];
                int y0  = (int)floorf(ys);
                int y0c = min(max(y0, 0), 127), y1c = min(max(y0+1, 0), 127);
                float wa = (float)y1c - ys;     // top tap weight
                float wc = ys - (float)y0c;     // bottom tap weight
                const unsigned short* pb = featbf + ((size_t)b << 20);
                const uint4* p0 = (const uint4*)(pb + (y0c*128 + x0)*64) + cq;
                const uint4* p1 = (const uint4*)(pb + (y1c*128 + x0)*64) + cq;
#pragma unroll
                for (int ci = 0; ci < 4; ci++) {
                    uint4 a = p0[ci], c = p1[ci];
                    uint4 u;
                    u.x = pack2bf(bflo(a.x)*wa + bflo(c.x)*wc, bfhi(a.x)*wa + bfhi(c.x)*wc);
                    u.y = pack2bf(bflo(a.y)*wa + bflo(c.y)*wc, bfhi(a.y)*wa + bfhi(c.y)*wc);
                    u.z = pack2bf(bflo(a.z)*wa + bflo(c.z)*wc, bfhi(a.z)*wa + bfhi(c.z)*wc);
                    u.w = pack2bf(bflo(a.w)*wa + bflo(c.w)*wc, bfhi(a.w)*wa + bfhi(c.w)*wc);
                    *(uint4*)(dst + ((bcol0 + ci*16) ^ ((hs & 7) << 4))) = u;
                }
            } else {
                uint4 z = make_uint4(0,0,0,0);
#pragma unroll
                for (int ci = 0; ci < 4; ci++)
                    *(uint4*)(dst + ((bcol0 + ci*16) ^ ((hs & 7) << 4))) = z;
            }
        }

        // ---- prefetch k+1 weights (latency hides under sync + MFMA) ----
        if (k < 8) {
            const uint4* src = (const uint4*)(wTbf + ((k+1) << 12));
            wv0 = src[t];
            wv1 = src[t + 256];
        }
        __syncthreads();

        // ---- MFMA: acc[mi][ni] += A[32k-slice] * B ----
#pragma unroll
        for (int ks = 0; ks < 2; ks++) {
            bf16x8 af[2], bfr[4];
#pragma unroll
            for (int mi = 0; mi < 2; mi++) {
                int h = m0 + mi*16 + lm;
                af[mi] = *(const bf16x8*)(lds_samp + h*128 + ((ks*64 + lk*16) ^ ((h & 7) << 4)));
            }
#pragma unroll
            for (int ni = 0; ni < 4; ni++) {
                int o = ni*16 + lm;
                bfr[ni] = *(const bf16x8*)(lds_wk + o*128 + ((ks*64 + lk*16) ^ ((o & 7) << 4)));
            }
#pragma unroll
            for (int mi = 0; mi < 2; mi++)
#pragma unroll
                for (int ni = 0; ni < 4; ni++)
                    acc[mi][ni] = __builtin_amdgcn_mfma_f32_16x16x32_bf16(af[mi], bfr[ni], acc[mi][ni], 0, 0, 0);
        }
    }

    // ---- epilogue: bias, bf16 xpre write (C/D: row=lk*4+reg, col=lm), GN stats ----
#pragma unroll
    for (int ni = 0; ni < 4; ni++) {
        int o = ni*16 + lm;
        float bias = b_dsc[o];
        float s1 = 0.f, s2 = 0.f;
#pragma unroll
        for (int mi = 0; mi < 2; mi++) {
            float4 r;
            r.x = acc[mi][ni][0] + bias;
            r.y = acc[mi][ni][1] + bias;
            r.z = acc[mi][ni][2] + bias;
            r.w = acc[mi][ni][3] + bias;
            s1 += r.x + r.y + r.z + r.w;
            s2 += r.x*r.x + r.y*r.y + r.z*r.z + r.w*r.w;
            int h = m0 + mi*16 + lk*4;
            uint2 u2;
            u2.x = pack2bf(r.x, r.y);
            u2.y = pack2bf(r.z, r.w);
            *(uint2*)(xprebf + (((b*64 + o) << 14) + (w << 7) + h)) = u2;
        }
        s1 += __shfl_xor(s1, 1);  s1 += __shfl_xor(s1, 2);
        s1 += __shfl_xor(s1, 16); s1 += __shfl_xor(s1, 32);
        s2 += __shfl_xor(s2, 1);  s2 += __shfl_xor(s2, 2);
        s2 += __shfl_xor(s2, 16); s2 += __shfl_xor(s2, 32);
        if (lk == 0 && (lm & 3) == 0) {
            atomicAdd(&red[ni*4 + (lm >> 2)][0], s1);
            atomicAdd(&red[ni*4 + (lm >> 2)][1], s2);
        }
    }
    __syncthreads();
    if (t < 16) {
        atomicAdd(&gstats[(b*16 + t)*2],   red[t][0]);
        atomicAdd(&gstats[(b*16 + t)*2+1], red[t][1]);
    }
}

// ---------------- GN finalize (folded) + apply + ReLU (bf16 in, fp32 out) ----------------
__global__ __launch_bounds__(256) void k_gn_apply(const unsigned short* __restrict__ xprebf,
                                                  const float* __restrict__ gstats,
                                                  const float* __restrict__ gn_gamma,
                                                  const float* __restrict__ gn_beta,
                                                  float* __restrict__ out) {
    int i8  = blockIdx.x*256 + threadIdx.x;
    int idx = i8 * 8;
    int o = (idx >> 14) & 63;
    int b = idx >> 20;
    int g = o >> 2;
    float n    = 65536.f;           // 4 ch * 128 * 128
    float mean = gstats[(b*16+g)*2] / n;
    float var  = gstats[(b*16+g)*2+1] / n - mean*mean;
    float istd = 1.0f / sqrtf(var + EPS_);
    float ga = gn_gamma[o] * istd;
    float be = gn_beta[o] - mean * ga;
    uint4 v = *(const uint4*)(xprebf + idx);
    float4 r0, r1;
    r0.x = fmaxf(bflo(v.x)*ga + be, 0.f);
    r0.y = fmaxf(bfhi(v.x)*ga + be, 0.f);
    r0.z = fmaxf(bflo(v.y)*ga + be, 0.f);
    r0.w = fmaxf(bfhi(v.y)*ga + be, 0.f);
    r1.x = fmaxf(bflo(v.z)*ga + be, 0.f);
    r1.y = fmaxf(bfhi(v.z)*ga + be, 0.f);
    r1.z = fmaxf(bflo(v.w)*ga + be, 0.f);
    r1.w = fmaxf(bfhi(v.w)*ga + be, 0.f);
    *(float4*)(out + idx)     = r0;
    *(float4*)(out + idx + 4) = r1;
}

extern "C" void kernel_launch(void* const* d_in, const int* in_sizes, int n_in,
                              void* d_out, int out_size, void* d_ws, size_t ws_size,
                              hipStream_t stream) {
    const float* f        = (const float*)d_in[0];
    const float* w_off    = (const float*)d_in[1];
    const float* bn_gamma = (const float*)d_in[3];
    const float* bn_beta  = (const float*)d_in[4];
    const float* w_dsc    = (const float*)d_in[5];
    const float* b_dsc    = (const float*)d_in[6];
    const float* gn_gamma = (const float*)d_in[7];
    const float* gn_beta  = (const float*)d_in[8];

    float* ws      = (float*)d_ws;
    unsigned short* featbf = (unsigned short*)(ws + FEATBF_OFF);
    unsigned short* xprebf = (unsigned short*)(ws + XPRE_OFF);
    float* off_pre = ws + OFFPRE_OFF;
    float* off_half= ws + OFFH_OFF;
    unsigned short* wTbf = (unsigned short*)(ws + WT_OFF);
    float* wP      = ws + WP_OFF;
    float* bnstats = ws + BNSTATS_OFF;
    float* gstats  = ws + GSTATS_OFF;

    hipMemsetAsync(bnstats, 0, STATS_BYTES, stream);

    k_nhwc<<<2048, 256, 0, stream>>>(f, featbf);
    k_wprep<<<165, 256, 0, stream>>>(w_dsc, wTbf, w_off, wP);
    k_conv_off<<<4096, 128, 0, stream>>>(f, wP, off_half);
    k_bn_stats<<<288, 256, 0, stream>>>(off_half, off_pre, bnstats);
    k_sample_dsc<<<1024, 256, 0, stream>>>(featbf, off_pre, bnstats, bn_gamma, bn_beta,
                                           wTbf, b_dsc, xprebf, gstats);
    k_gn_apply<<<4096, 256, 0, stream>>>(xprebf, gstats, gn_gamma, gn_beta, (float*)d_out);
}